// Round 6
// baseline (64.333 us; speedup 1.0000x reference)
//
#include <hip/hip_runtime.h>

#define N_PTS 20000
#define NA 20480            // candidates padded to 1280 tiles of 16
#define NB 20032            // queries padded to 313 wave-groups of 64
#define TILES_TOTAL 1280    // 16-candidate tiles
#define A_BYTES  (NA * 32 * 2)            // 1,310,720
#define B_BYTES  (NB * 32 * 2)            // 1,282,048
#define PART_OFF (A_BYTES + B_BYTES)      // 2,592,768

typedef __attribute__((ext_vector_type(8))) short bf16x8;
typedef __attribute__((ext_vector_type(4))) float f32x4;

static __device__ __forceinline__ unsigned short f2bf(float f) {
    unsigned int u = __float_as_uint(f);
    unsigned int r = (u + 0x7FFFu + ((u >> 16) & 1u)) >> 16;   // RNE
    return (unsigned short)r;
}
static __device__ __forceinline__ float bf2f(unsigned short h) {
    return __uint_as_float(((unsigned int)h) << 16);
}

// A row (candidate m), K=32 slots (11 used):
//   0-2: -2*c_hi (pairs q_hi) | 3-5: -2*c_hi (pairs q_lo) | 6-8: -2*c_lo (pairs q_hi)
//   9,10: y2 hi/lo (pair with 1.0); rest 0
// => acc ~= ||y||^2 - 2 x.y  (argmin key; x^2 constant per query)
__global__ __launch_bounds__(256) void nn_prep(const float* __restrict__ q,
                                               const float* __restrict__ c,
                                               unsigned short* __restrict__ Amat,
                                               unsigned short* __restrict__ Bmat) {
    const int m = blockIdx.x * 256 + (int)threadIdx.x;
    if (m < NA) {
        unsigned short a[32];
        #pragma unroll
        for (int r = 0; r < 32; ++r) a[r] = 0;
        if (m < N_PTS) {
            const float cx = c[m * 3 + 0], cy = c[m * 3 + 1], cz = c[m * 3 + 2];
            const unsigned short hx = f2bf(cx), hy = f2bf(cy), hz = f2bf(cz);
            const float lx = cx - bf2f(hx), ly = cy - bf2f(hy), lz = cz - bf2f(hz);
            const float y2 = fmaf(cx, cx, fmaf(cy, cy, cz * cz));
            const unsigned short y2h = f2bf(y2);
            const unsigned short y2l = f2bf(y2 - bf2f(y2h));
            a[0] = f2bf(-2.f * bf2f(hx)); a[1] = f2bf(-2.f * bf2f(hy)); a[2] = f2bf(-2.f * bf2f(hz));
            a[3] = a[0]; a[4] = a[1]; a[5] = a[2];
            a[6] = f2bf(-2.f * lx); a[7] = f2bf(-2.f * ly); a[8] = f2bf(-2.f * lz);
            a[9] = y2h; a[10] = y2l;
        } else {
            a[9] = f2bf(1e30f);   // padded candidates: huge key, never wins
        }
        unsigned int* o = (unsigned int*)(Amat + (size_t)m * 32);
        #pragma unroll
        for (int r = 0; r < 16; ++r)
            o[r] = (unsigned int)a[2 * r] | ((unsigned int)a[2 * r + 1] << 16);
    }
    if (m < NB) {
        unsigned short b[32];
        #pragma unroll
        for (int r = 0; r < 32; ++r) b[r] = 0;
        if (m < N_PTS) {
            const float qx = q[m * 3 + 0], qy = q[m * 3 + 1], qz = q[m * 3 + 2];
            const unsigned short hx = f2bf(qx), hy = f2bf(qy), hz = f2bf(qz);
            b[0] = hx; b[1] = hy; b[2] = hz;
            b[3] = f2bf(qx - bf2f(hx)); b[4] = f2bf(qy - bf2f(hy)); b[5] = f2bf(qz - bf2f(hz));
            b[6] = hx; b[7] = hy; b[8] = hz;
            b[9] = f2bf(1.0f); b[10] = f2bf(1.0f);
        }
        unsigned int* o = (unsigned int*)(Bmat + (size_t)m * 32);
        #pragma unroll
        for (int r = 0; r < 16; ++r)
            o[r] = (unsigned int)b[2 * r] | ((unsigned int)b[2 * r + 1] << 16);
    }
}

// plain-C pack -> v_bfi_b32; tag in ordered low bits => fmin ties auto-pick smaller tile
template<unsigned KEYM, unsigned TAGM>
static __device__ __forceinline__ float packkey(float x, unsigned tag) {
    return __uint_as_float((__float_as_uint(x) & KEYM) | (tag & TAGM));
}

// Block = 4 waves sharing ONE candidate chunk (L1 reuse), different query groups.
// Wave: 64 queries (4 B-frags of 16) x TPC tiles of 16 candidates.
// mfma_f32_16x16x32_bf16: A row=lane&15,k=(lane>>4)*8+j; C/D col=lane&15,row=(lane>>4)*4+reg (m89)
template<int LC>
__global__ __launch_bounds__(256, 4) void nn_main(const unsigned short* __restrict__ Amat,
                                                  const unsigned short* __restrict__ Bmat,
                                                  float2* __restrict__ partial) {
    constexpr int C = 1 << LC;
    constexpr int TPC = TILES_TOTAL >> LC;
    constexpr unsigned TB = (TPC <= 32) ? 5u : (TPC <= 64) ? 6u : (TPC <= 128) ? 7u :
                            (TPC <= 256) ? 8u : (TPC <= 512) ? 9u : 10u;
    constexpr unsigned TAGM = (1u << TB) - 1u;
    constexpr unsigned KEYM = ~TAGM;

    const int wav = (int)(threadIdx.x >> 6);
    const int ch = blockIdx.x & (C - 1);
    const int qg = ((int)blockIdx.x >> LC) * 4 + wav;
    if (qg >= 313) return;
    const int lane = (int)(threadIdx.x & 63);
    const int qbase = qg * 64;
    const int l15 = lane & 15;
    const int rg = lane >> 4;            // row group 0..3

    bf16x8 bq[4];
    #pragma unroll
    for (int qf = 0; qf < 4; ++qf)
        bq[qf] = *(const bf16x8*)(Bmat + (size_t)(qbase + qf * 16 + l15) * 32 + rg * 8);

    const f32x4 zacc = {0.f, 0.f, 0.f, 0.f};

    float vmin[16];
    #pragma unroll
    for (int r = 0; r < 16; ++r) vmin[r] = __uint_as_float(0x7F800000u);

    const unsigned short* Ap = Amat + ((size_t)(ch * TPC) * 16 + l15) * 32 + rg * 8;
    for (int t = 0; t < TPC; t += 2) {
        const bf16x8 af0 = *(const bf16x8*)Ap;
        const bf16x8 af1 = *(const bf16x8*)(Ap + 512);
        Ap += 1024;                       // 2 tiles * 16 rows * 32 shorts
        #pragma unroll
        for (int qf = 0; qf < 4; ++qf) {
            const f32x4 a0 = __builtin_amdgcn_mfma_f32_16x16x32_bf16(af0, bq[qf], zacc, 0, 0, 0);
            const f32x4 a1 = __builtin_amdgcn_mfma_f32_16x16x32_bf16(af1, bq[qf], zacc, 0, 0, 0);
            #pragma unroll
            for (int r = 0; r < 4; ++r) {
                const float p0 = packkey<KEYM, TAGM>(a0[r], (unsigned)t);
                const float p1 = packkey<KEYM, TAGM>(a1[r], (unsigned)(t + 1));
                vmin[qf * 4 + r] = fminf(fminf(vmin[qf * 4 + r], p0), p1);   // v_min3_f32
            }
        }
    }

    // epilogue: per qfrag, fold 4 regs (rows asc) then merge 4 row-group lanes
    #pragma unroll
    for (int qf = 0; qf < 4; ++qf) {
        float bv = __uint_as_float(0x7F800000u);
        int bi = 0x7FFFFFFF;
        #pragma unroll
        for (int r = 0; r < 4; ++r) {
            const float v = vmin[qf * 4 + r];
            const int tg = (int)(__float_as_uint(v) & TAGM);
            const int id = (ch * TPC + tg) * 16 + rg * 4 + r;
            if (v < bv || (v == bv && id < bi)) { bv = v; bi = id; }
        }
        #pragma unroll
        for (int m = 16; m <= 32; m <<= 1) {
            const float ov = __shfl_xor(bv, m);
            const int oi = __shfl_xor(bi, m);
            if (ov < bv || (ov == bv && oi < bi)) { bv = ov; bi = oi; }
        }
        if (rg == 0)
            partial[(size_t)(qbase + qf * 16 + l15) * C + ch] = make_float2(bv, __int_as_float(bi));
    }
}

// Reduce chunks per query, count mismatches, last block writes the loss.
__global__ __launch_bounds__(256) void nn_reduce(const float2* __restrict__ partial,
                                                 const int* __restrict__ labels,
                                                 unsigned int* __restrict__ count,
                                                 unsigned int* __restrict__ ticket,
                                                 float* __restrict__ out, int C) {
    const int i = blockIdx.x * 256 + (int)threadIdx.x;
    int mism = 0;
    if (i < N_PTS) {
        float best = __uint_as_float(0x7F800000u);
        int bidx = 0;
        for (int c = 0; c < C; ++c) {                       // ascending chunk, strict <
            const float2 p = partial[(size_t)i * C + c];
            if (p.x < best) { best = p.x; bidx = __float_as_int(p.y); }
        }
        mism = (labels[bidx] != labels[i]) ? 1 : 0;
    }
    const unsigned long long msk = __ballot(mism != 0);
    __shared__ unsigned int bsum;
    if (threadIdx.x == 0) bsum = 0;
    __syncthreads();
    if ((threadIdx.x & 63) == 0) atomicAdd(&bsum, (unsigned)__popcll(msk));
    __syncthreads();
    if (threadIdx.x == 0) {
        atomicAdd(count, bsum);
        __threadfence();
        const unsigned t = atomicAdd(ticket, 1u);
        if (t == gridDim.x - 1) {
            __threadfence();
            const unsigned total = atomicAdd(count, 0u);
            out[0] = (float)total / (float)N_PTS;
        }
    }
}

extern "C" void kernel_launch(void* const* d_in, const int* in_sizes, int n_in,
                              void* d_out, int out_size, void* d_ws, size_t ws_size,
                              hipStream_t stream) {
    const float* mean_3d      = (const float*)d_in[0];
    const float* mean_3d_cano = (const float*)d_in[1];
    const int*   segm_labels  = (const int*)d_in[2];
    float* out = (float*)d_out;

    unsigned short* Amat = (unsigned short*)d_ws;
    unsigned short* Bmat = (unsigned short*)((char*)d_ws + A_BYTES);
    float2* partial = (float2*)((char*)d_ws + PART_OFF);

    int lc = 5;                                             // prefer 32 chunks
    while (lc > 0 && (size_t)PART_OFF + (size_t)NB * (1ull << lc) * 8ull + 8ull > ws_size) --lc;
    const int C = 1 << lc;
    unsigned int* count = (unsigned int*)((char*)d_ws + PART_OFF + (size_t)NB * (size_t)C * 8ull);

    (void)hipMemsetAsync(count, 0, 2 * sizeof(unsigned int), stream);   // count + ticket
    nn_prep<<<NA / 256, 256, 0, stream>>>(mean_3d, mean_3d_cano, Amat, Bmat);

    const int blocks = C * 79;                              // 4 query-groups per block
    switch (lc) {
        case 5: nn_main<5><<<blocks, 256, 0, stream>>>(Amat, Bmat, partial); break;
        case 4: nn_main<4><<<blocks, 256, 0, stream>>>(Amat, Bmat, partial); break;
        case 3: nn_main<3><<<blocks, 256, 0, stream>>>(Amat, Bmat, partial); break;
        case 2: nn_main<2><<<blocks, 256, 0, stream>>>(Amat, Bmat, partial); break;
        case 1: nn_main<1><<<blocks, 256, 0, stream>>>(Amat, Bmat, partial); break;
        default: nn_main<0><<<blocks, 256, 0, stream>>>(Amat, Bmat, partial); break;
    }
    nn_reduce<<<(N_PTS + 255) / 256, 256, 0, stream>>>(partial, segm_labels, count, count + 1, out, C);
}

// Round 7
// 64.319 us; speedup vs baseline: 1.0002x; 1.0002x over previous
//
#include <hip/hip_runtime.h>

#define N_PTS 20000
#define NA 20480            // candidates padded to 1280 tiles of 16
#define NB 20032            // queries padded to 313 wave-groups of 64
#define TILES_TOTAL 1280    // 16-candidate tiles
#define A_BYTES  (NA * 32 * 2)            // 1,310,720
#define B_BYTES  (NB * 32 * 2)            // 1,282,048
#define PART_OFF (A_BYTES + B_BYTES)      // 2,592,768

typedef __attribute__((ext_vector_type(8))) short bf16x8;
typedef __attribute__((ext_vector_type(4))) float f32x4;

static __device__ __forceinline__ unsigned short f2bf(float f) {
    unsigned int u = __float_as_uint(f);
    unsigned int r = (u + 0x7FFFu + ((u >> 16) & 1u)) >> 16;   // RNE
    return (unsigned short)r;
}
static __device__ __forceinline__ float bf2f(unsigned short h) {
    return __uint_as_float(((unsigned int)h) << 16);
}

// zero-cost register-class pin: force value into arch VGPRs (no instruction emitted)
static __device__ __forceinline__ f32x4 pin(f32x4 v) {
    asm("" : "+v"(v));
    return v;
}

// A row (candidate m), K=32 slots (11 used):
//   0-2: -2*c_hi (pairs q_hi) | 3-5: -2*c_hi (pairs q_lo) | 6-8: -2*c_lo (pairs q_hi)
//   9,10: y2 hi/lo (pair with 1.0); rest 0
// => acc ~= ||y||^2 - 2 x.y  (argmin key; x^2 constant per query)
__global__ __launch_bounds__(256) void nn_prep(const float* __restrict__ q,
                                               const float* __restrict__ c,
                                               unsigned short* __restrict__ Amat,
                                               unsigned short* __restrict__ Bmat) {
    const int m = blockIdx.x * 256 + (int)threadIdx.x;
    if (m < NA) {
        unsigned short a[32];
        #pragma unroll
        for (int r = 0; r < 32; ++r) a[r] = 0;
        if (m < N_PTS) {
            const float cx = c[m * 3 + 0], cy = c[m * 3 + 1], cz = c[m * 3 + 2];
            const unsigned short hx = f2bf(cx), hy = f2bf(cy), hz = f2bf(cz);
            const float lx = cx - bf2f(hx), ly = cy - bf2f(hy), lz = cz - bf2f(hz);
            const float y2 = fmaf(cx, cx, fmaf(cy, cy, cz * cz));
            const unsigned short y2h = f2bf(y2);
            const unsigned short y2l = f2bf(y2 - bf2f(y2h));
            a[0] = f2bf(-2.f * bf2f(hx)); a[1] = f2bf(-2.f * bf2f(hy)); a[2] = f2bf(-2.f * bf2f(hz));
            a[3] = a[0]; a[4] = a[1]; a[5] = a[2];
            a[6] = f2bf(-2.f * lx); a[7] = f2bf(-2.f * ly); a[8] = f2bf(-2.f * lz);
            a[9] = y2h; a[10] = y2l;
        } else {
            a[9] = f2bf(1e30f);   // padded candidates: huge key, never wins
        }
        unsigned int* o = (unsigned int*)(Amat + (size_t)m * 32);
        #pragma unroll
        for (int r = 0; r < 16; ++r)
            o[r] = (unsigned int)a[2 * r] | ((unsigned int)a[2 * r + 1] << 16);
    }
    if (m < NB) {
        unsigned short b[32];
        #pragma unroll
        for (int r = 0; r < 32; ++r) b[r] = 0;
        if (m < N_PTS) {
            const float qx = q[m * 3 + 0], qy = q[m * 3 + 1], qz = q[m * 3 + 2];
            const unsigned short hx = f2bf(qx), hy = f2bf(qy), hz = f2bf(qz);
            b[0] = hx; b[1] = hy; b[2] = hz;
            b[3] = f2bf(qx - bf2f(hx)); b[4] = f2bf(qy - bf2f(hy)); b[5] = f2bf(qz - bf2f(hz));
            b[6] = hx; b[7] = hy; b[8] = hz;
            b[9] = f2bf(1.0f); b[10] = f2bf(1.0f);
        }
        unsigned int* o = (unsigned int*)(Bmat + (size_t)m * 32);
        #pragma unroll
        for (int r = 0; r < 16; ++r)
            o[r] = (unsigned int)b[2 * r] | ((unsigned int)b[2 * r + 1] << 16);
    }
}

// pack: (acc & KEYM) | tag -> single v_and_or_b32 (KEYM in SGPR, tag inline const)
template<unsigned KEYM, unsigned TAGM>
static __device__ __forceinline__ float packkey(float x, unsigned tag) {
    return __uint_as_float((__float_as_uint(x) & KEYM) | (tag & TAGM));
}

// Block = 4 waves sharing ONE candidate chunk (L1 reuse), different query groups.
// Wave: 64 queries (4 B-frags of 16) x TPC tiles of 16 candidates.
// mfma_f32_16x16x32_bf16: A row=lane&15,k=(lane>>4)*8+j; C/D col=lane&15,row=(lane>>4)*4+reg (m89)
template<int LC>
__global__ __launch_bounds__(256, 4) void nn_main(const unsigned short* __restrict__ Amat,
                                                  const unsigned short* __restrict__ Bmat,
                                                  float2* __restrict__ partial) {
    constexpr int C = 1 << LC;
    constexpr int TPC = TILES_TOTAL >> LC;
    constexpr unsigned TB = (TPC <= 32) ? 5u : (TPC <= 64) ? 6u : (TPC <= 128) ? 7u :
                            (TPC <= 256) ? 8u : (TPC <= 512) ? 9u : 10u;
    constexpr unsigned TAGM = (1u << TB) - 1u;
    constexpr unsigned KEYM = ~TAGM;

    const int wav = (int)(threadIdx.x >> 6);
    const int ch = blockIdx.x & (C - 1);
    const int qg = ((int)blockIdx.x >> LC) * 4 + wav;
    if (qg >= 313) return;
    const int lane = (int)(threadIdx.x & 63);
    const int qbase = qg * 64;
    const int l15 = lane & 15;
    const int rg = lane >> 4;            // row group 0..3

    bf16x8 bq[4];
    #pragma unroll
    for (int qf = 0; qf < 4; ++qf)
        bq[qf] = *(const bf16x8*)(Bmat + (size_t)(qbase + qf * 16 + l15) * 32 + rg * 8);

    f32x4 zacc = {0.f, 0.f, 0.f, 0.f};
    zacc = pin(zacc);

    float vmin[16];
    #pragma unroll
    for (int r = 0; r < 16; ++r) vmin[r] = __uint_as_float(0x7F800000u);

    const unsigned short* Ap = Amat + ((size_t)(ch * TPC) * 16 + l15) * 32 + rg * 8;
    for (int t = 0; t < TPC; t += 2) {
        const bf16x8 af0 = *(const bf16x8*)Ap;
        const bf16x8 af1 = *(const bf16x8*)(Ap + 512);
        Ap += 1024;                       // 2 tiles * 16 rows * 32 shorts
        #pragma unroll
        for (int qf = 0; qf < 4; ++qf) {
            f32x4 a0 = __builtin_amdgcn_mfma_f32_16x16x32_bf16(af0, bq[qf], zacc, 0, 0, 0);
            a0 = pin(a0);                 // keep accumulator in arch VGPRs
            f32x4 a1 = __builtin_amdgcn_mfma_f32_16x16x32_bf16(af1, bq[qf], zacc, 0, 0, 0);
            a1 = pin(a1);
            #pragma unroll
            for (int r = 0; r < 4; ++r) {
                const float p0 = packkey<KEYM, TAGM>(a0[r], (unsigned)t);
                const float p1 = packkey<KEYM, TAGM>(a1[r], (unsigned)(t + 1));
                vmin[qf * 4 + r] = fminf(fminf(vmin[qf * 4 + r], p0), p1);   // v_min3_f32
            }
        }
    }

    // epilogue: per qfrag, fold 4 regs (rows asc) then merge 4 row-group lanes
    #pragma unroll
    for (int qf = 0; qf < 4; ++qf) {
        float bv = __uint_as_float(0x7F800000u);
        int bi = 0x7FFFFFFF;
        #pragma unroll
        for (int r = 0; r < 4; ++r) {
            const float v = vmin[qf * 4 + r];
            const int tg = (int)(__float_as_uint(v) & TAGM);
            const int id = (ch * TPC + tg) * 16 + rg * 4 + r;
            if (v < bv || (v == bv && id < bi)) { bv = v; bi = id; }
        }
        #pragma unroll
        for (int m = 16; m <= 32; m <<= 1) {
            const float ov = __shfl_xor(bv, m);
            const int oi = __shfl_xor(bi, m);
            if (ov < bv || (ov == bv && oi < bi)) { bv = ov; bi = oi; }
        }
        if (rg == 0)   // [ch][query] layout: consecutive queries -> coalesced
            partial[(size_t)ch * NB + (qbase + qf * 16 + l15)] = make_float2(bv, __int_as_float(bi));
    }
}

// Reduce chunks per query, count mismatches, last block writes the loss.
__global__ __launch_bounds__(256) void nn_reduce(const float2* __restrict__ partial,
                                                 const int* __restrict__ labels,
                                                 unsigned int* __restrict__ count,
                                                 unsigned int* __restrict__ ticket,
                                                 float* __restrict__ out, int C) {
    const int i = blockIdx.x * 256 + (int)threadIdx.x;
    int mism = 0;
    if (i < N_PTS) {
        float best = __uint_as_float(0x7F800000u);
        int bidx = 0;
        for (int c = 0; c < C; ++c) {                       // ascending chunk, strict <
            const float2 p = partial[(size_t)c * NB + i];   // coalesced per chunk
            if (p.x < best) { best = p.x; bidx = __float_as_int(p.y); }
        }
        mism = (labels[bidx] != labels[i]) ? 1 : 0;
    }
    const unsigned long long msk = __ballot(mism != 0);
    __shared__ unsigned int bsum;
    if (threadIdx.x == 0) bsum = 0;
    __syncthreads();
    if ((threadIdx.x & 63) == 0) atomicAdd(&bsum, (unsigned)__popcll(msk));
    __syncthreads();
    if (threadIdx.x == 0) {
        atomicAdd(count, bsum);
        __threadfence();
        const unsigned t = atomicAdd(ticket, 1u);
        if (t == gridDim.x - 1) {
            __threadfence();
            const unsigned total = atomicAdd(count, 0u);
            out[0] = (float)total / (float)N_PTS;
        }
    }
}

extern "C" void kernel_launch(void* const* d_in, const int* in_sizes, int n_in,
                              void* d_out, int out_size, void* d_ws, size_t ws_size,
                              hipStream_t stream) {
    const float* mean_3d      = (const float*)d_in[0];
    const float* mean_3d_cano = (const float*)d_in[1];
    const int*   segm_labels  = (const int*)d_in[2];
    float* out = (float*)d_out;

    unsigned short* Amat = (unsigned short*)d_ws;
    unsigned short* Bmat = (unsigned short*)((char*)d_ws + A_BYTES);
    float2* partial = (float2*)((char*)d_ws + PART_OFF);

    int lc = 5;                                             // prefer 32 chunks
    while (lc > 0 && (size_t)PART_OFF + (size_t)NB * (1ull << lc) * 8ull + 8ull > ws_size) --lc;
    const int C = 1 << lc;
    unsigned int* count = (unsigned int*)((char*)d_ws + PART_OFF + (size_t)NB * (size_t)C * 8ull);

    (void)hipMemsetAsync(count, 0, 2 * sizeof(unsigned int), stream);   // count + ticket
    nn_prep<<<NA / 256, 256, 0, stream>>>(mean_3d, mean_3d_cano, Amat, Bmat);

    const int blocks = C * 79;                              // 4 query-groups per block
    switch (lc) {
        case 5: nn_main<5><<<blocks, 256, 0, stream>>>(Amat, Bmat, partial); break;
        case 4: nn_main<4><<<blocks, 256, 0, stream>>>(Amat, Bmat, partial); break;
        case 3: nn_main<3><<<blocks, 256, 0, stream>>>(Amat, Bmat, partial); break;
        case 2: nn_main<2><<<blocks, 256, 0, stream>>>(Amat, Bmat, partial); break;
        case 1: nn_main<1><<<blocks, 256, 0, stream>>>(Amat, Bmat, partial); break;
        default: nn_main<0><<<blocks, 256, 0, stream>>>(Amat, Bmat, partial); break;
    }
    nn_reduce<<<(N_PTS + 255) / 256, 256, 0, stream>>>(partial, segm_labels, count, count + 1, out, C);
}